// Round 1
// baseline (181.437 us; speedup 1.0000x reference)
//
#include <hip/hip_runtime.h>

// Problem constants (from reference): B=16, T=2048, D=1024, H=512, N_SPANS=256
#define T_CONST   2048
#define D_CONST   1024
#define H_CONST   512
#define NS_CONST  256

// One block per (b, span) pair. 128 threads; thread t owns float4 #t of the
// H=512-float segment (128 * 4 = 512). All loads/stores coalesced float4.
__global__ __launch_bounds__(128) void minus_span_kernel(
    const float* __restrict__ input,     // (B, T, D) fp32
    const int*   __restrict__ span_idxs, // (B, NS, 2) int32 (harness contract)
    float*       __restrict__ out)       // (B, NS, 4*H) fp32
{
    const int bs = blockIdx.x;              // b * NS + s
    const int b  = bs >> 8;                 // NS == 256
    const int i  = span_idxs[bs * 2 + 0];
    const int j  = span_idxs[bs * 2 + 1];
    const int h  = threadIdx.x;             // float4 index within H-row, 0..127

    // Base of this batch's (T, D) slab, viewed as float4. Row stride = D/4 = 256.
    const float4* base = reinterpret_cast<const float4*>(input) + (size_t)b * T_CONST * (D_CONST / 4);

    const float4 zero = make_float4(0.f, 0.f, 0.f, 0.f);

    // fwd part = cols [0, 512)  -> float4 offset [0, 128)
    // bwd part = cols [512,1024)-> float4 offset [128, 256)
    float4 f_end   = base[(size_t)j * 256 + h];
    float4 b_start = base[(size_t)i * 256 + 128 + h];
    float4 f_pre   = (i >= 1)        ? base[(size_t)(i - 1) * 256 + h]       : zero;
    float4 b_post  = (j + 1 < T_CONST) ? base[(size_t)(j + 1) * 256 + 128 + h] : zero;

    float4 o0 = make_float4(f_end.x - f_pre.x,  f_end.y - f_pre.y,
                            f_end.z - f_pre.z,  f_end.w - f_pre.w);
    float4 o1 = make_float4(b_start.x - b_post.x, b_start.y - b_post.y,
                            b_start.z - b_post.z, b_start.w - b_post.w);
    float4 o2 = f_pre;
    float4 o3 = b_post;

    if (i == 0 && j == 0) {                 // skip-span: whole output row is 0
        o0 = zero; o1 = zero; o2 = zero; o3 = zero;
    }

    // Output row: 4*H = 2048 floats = 512 float4 per (b,s)
    float4* ob = reinterpret_cast<float4*>(out) + (size_t)bs * 512;
    ob[h]       = o0;   // f_end - f_pre
    ob[128 + h] = o1;   // b_start - b_post
    ob[256 + h] = o2;   // f_pre
    ob[384 + h] = o3;   // b_post
}

extern "C" void kernel_launch(void* const* d_in, const int* in_sizes, int n_in,
                              void* d_out, int out_size, void* d_ws, size_t ws_size,
                              hipStream_t stream) {
    const float* input     = (const float*)d_in[0];
    const int*   span_idxs = (const int*)d_in[1];
    float*       out       = (float*)d_out;

    const int n_blocks = 16 * NS_CONST;   // B * N_SPANS = 4096
    minus_span_kernel<<<n_blocks, 128, 0, stream>>>(input, span_idxs, out);
}

// Round 3
// 181.398 us; speedup vs baseline: 1.0002x; 1.0002x over previous
//
#include <hip/hip_runtime.h>

// Problem constants (from reference): B=16, T=2048, D=1024, H=512, N_SPANS=256
#define T_CONST   2048
#define D_CONST   1024
#define H_CONST   512
#define NS_CONST  256

// Native vector type (HIP's float4 is a class; nontemporal builtin needs this)
typedef float v4f __attribute__((ext_vector_type(4)));

// One block per (b, span) pair. 128 threads; thread t owns float4 #t of the
// H=512-float segment (128 * 4 = 512). All loads/stores coalesced 16B.
// Output stores are non-temporal: write-once, keep L2 for gathered input rows.
__global__ __launch_bounds__(128) void minus_span_kernel(
    const float* __restrict__ input,     // (B, T, D) fp32
    const int*   __restrict__ span_idxs, // (B, NS, 2) int32 (harness contract)
    float*       __restrict__ out)       // (B, NS, 4*H) fp32
{
    const int bs = blockIdx.x;              // b * NS + s
    const int b  = bs >> 8;                 // NS == 256

    // Block-uniform span indices: single load, broadcast to SGPRs.
    const int i = __builtin_amdgcn_readfirstlane(span_idxs[bs * 2 + 0]);
    const int j = __builtin_amdgcn_readfirstlane(span_idxs[bs * 2 + 1]);

    const int h = threadIdx.x;              // float4 index within H-row, 0..127

    // Base of this batch's (T, D) slab, viewed as v4f. Row stride = D/4 = 256.
    const v4f* base = reinterpret_cast<const v4f*>(input) + (size_t)b * T_CONST * (D_CONST / 4);

    const v4f zero = (v4f){0.f, 0.f, 0.f, 0.f};

    // fwd part = cols [0, 512)   -> float4 offset [0, 128)
    // bwd part = cols [512,1024) -> float4 offset [128, 256)
    v4f f_end   = base[(size_t)j * 256 + h];
    v4f b_start = base[(size_t)i * 256 + 128 + h];
    v4f f_pre   = (i >= 1)          ? base[(size_t)(i - 1) * 256 + h]       : zero;
    v4f b_post  = (j + 1 < T_CONST) ? base[(size_t)(j + 1) * 256 + 128 + h] : zero;

    v4f o0 = f_end   - f_pre;
    v4f o1 = b_start - b_post;
    v4f o2 = f_pre;
    v4f o3 = b_post;

    if (i == 0 && j == 0) {                 // skip-span: whole output row is 0
        o0 = zero; o1 = zero; o2 = zero; o3 = zero;
    }

    // Output row: 4*H = 2048 floats = 512 float4 per (b,s). Non-temporal.
    v4f* ob = reinterpret_cast<v4f*>(out) + (size_t)bs * 512;
    __builtin_nontemporal_store(o0, &ob[h]);
    __builtin_nontemporal_store(o1, &ob[128 + h]);
    __builtin_nontemporal_store(o2, &ob[256 + h]);
    __builtin_nontemporal_store(o3, &ob[384 + h]);
}

extern "C" void kernel_launch(void* const* d_in, const int* in_sizes, int n_in,
                              void* d_out, int out_size, void* d_ws, size_t ws_size,
                              hipStream_t stream) {
    const float* input     = (const float*)d_in[0];
    const int*   span_idxs = (const int*)d_in[1];
    float*       out       = (float*)d_out;

    const int n_blocks = 16 * NS_CONST;   // B * N_SPANS = 4096
    minus_span_kernel<<<n_blocks, 128, 0, stream>>>(input, span_idxs, out);
}